// Round 2
// baseline (66.816 us; speedup 1.0000x reference)
//
#include <hip/hip_runtime.h>

// Fused two-stage grouped conv, (1,512,14,14) fp32.
// Stage 1: t4[k,o,m,n] = sum_{i<64,j<3} x[(i*8+o), (m+j-2) mod 14, n] * w1[k,i,j]
//          (term valid only when 0 <= m+j-1 < 14; the mod-14 comes from roll(+1,H))
// Stage 2: out[i2*16+o2, m, n] = sum_{j<8,k<3} t4[o2,j,m,n+k-1] * w2[i2,j,k]  (zero-pad W)
//
// Block per (m, o2): stage-1 slice t4[o2,:,m,:] (112 vals) lives in LDS; no
// inter-block redundancy (k=o2 partitions stage 1 exactly). 224 blocks ~ 1/CU.

__global__ __launch_bounds__(128) void fused_shift_conv(
    const float* __restrict__ x,   // (512,14,14)
    const float* __restrict__ w1,  // (16,64,3)
    const float* __restrict__ w2,  // (32,8,3)
    float* __restrict__ out)       // (512,14,14)
{
    const int bx = blockIdx.x;     // 0..223
    const int m  = bx >> 4;        // 0..13
    const int o2 = bx & 15;        // 0..15  (== stage-1 output k)
    const int t  = threadIdx.x;    // 0..127

    __shared__ float w1s[64 * 3];      // w1[o2,:,:]
    __shared__ float w2s[32 * 8 * 3];  // full w2
    __shared__ float t4s[8 * 14];      // t4[o2, j, m, n] for this block

    // BUG FIX vs R0: block has 128 threads; stage these with grid-stride loops
    for (int idx = t; idx < 192; idx += 128) w1s[idx] = w1[o2 * 192 + idx];
    for (int idx = t; idx < 768; idx += 128) w2s[idx] = w2[idx];
    __syncthreads();

    // ---- stage 1: 8*14 = 112 outputs ----
    if (t < 112) {
        const int o = t / 14;      // 0..7  (group channel -> stage-2 'j')
        const int n = t % 14;
        float acc = 0.f;
        #pragma unroll
        for (int j = 0; j < 3; ++j) {
            const int hp = m + j - 1;          // padded-H index
            if (hp < 0 || hp >= 14) continue;  // zero pad (uniform branch)
            const int row = (hp + 13) % 14;    // undo roll(+1)
            const float* xp = x + (size_t)o * 196 + row * 14 + n;
            const float* wp = w1s + j;
            #pragma unroll
            for (int i = 0; i < 64; ++i) {
                acc += xp[(size_t)i * 8 * 196] * wp[i * 3];
            }
        }
        t4s[t] = acc;   // t = o*14 + n
    }
    __syncthreads();

    // ---- stage 2: 32*14 = 448 outputs ----
    for (int idx = t; idx < 448; idx += 128) {
        const int n  = idx % 14;
        const int i2 = idx / 14;   // 0..31
        const float* wp = w2s + i2 * 24;
        float acc = 0.f;
        #pragma unroll
        for (int j = 0; j < 8; ++j) {
            const float* tp = t4s + j * 14;
            #pragma unroll
            for (int k = 0; k < 3; ++k) {
                const int nn = n + k - 1;
                if (nn >= 0 && nn < 14) acc += tp[nn] * wp[j * 3 + k];
            }
        }
        out[((size_t)(i2 * 16 + o2) * 14 + m) * 14 + n] = acc;
    }
}

extern "C" void kernel_launch(void* const* d_in, const int* in_sizes, int n_in,
                              void* d_out, int out_size, void* d_ws, size_t ws_size,
                              hipStream_t stream) {
    const float* x  = (const float*)d_in[0];
    const float* w1 = (const float*)d_in[1];
    const float* w2 = (const float*)d_in[2];
    float* out = (float*)d_out;
    fused_shift_conv<<<dim3(224), dim3(128), 0, stream>>>(x, w1, w2, out);
}

// Round 3
// 59.992 us; speedup vs baseline: 1.1137x; 1.1137x over previous
//
#include <hip/hip_runtime.h>

// Fused two-stage grouped conv, (1,512,14,14) fp32.
// Stage 1: t4[k,o,m,n] = sum_{i<64,j<3} x[(i*8+o), (m+j-2) mod 14, n] * w1[k,i,j]
//          (term valid only when 0 <= m+j-1 < 14; the mod-14 comes from roll(+1,H))
// Stage 2: out[i2*16+o2, m, n] = sum_{j<8,k<3} t4[o2,j,m,n+k-1] * w2[i2,j,k]  (zero-pad W)
//
// Block per (m, o2). Latency-bound problem (14.5 MFLOP, 0.8 MB I/O), so the
// design goal is memory-level parallelism: stage-1's 192-deep load chain is
// split 4-way across threads (512-thread block, 448 active stage-1 lanes,
// 48 loads each, 8 waves/CU) with an LDS partial-sum combine.

__global__ __launch_bounds__(512) void fused_shift_conv(
    const float* __restrict__ x,   // (512,14,14)
    const float* __restrict__ w1,  // (16,64,3)
    const float* __restrict__ w2,  // (32,8,3)
    float* __restrict__ out)       // (512,14,14)
{
    const int bx = blockIdx.x;     // 0..223
    const int m  = bx >> 4;        // 0..13
    const int o2 = bx & 15;        // 0..15  (== stage-1 output k)
    const int t  = threadIdx.x;    // 0..511

    __shared__ float w1s[64 * 3];      // w1[o2,:,:]
    __shared__ float w2s[32 * 8 * 3];  // full w2
    __shared__ float t4p[4][112];      // stage-1 partials (i split 4-way)
    __shared__ float t4s[112];         // combined t4[o2, j(=o), m, n]

    if (t < 192) w1s[t] = w1[o2 * 192 + t];
    if (t >= 256 && t < 256 + 192) {   // different wave-group stages w2 (768 floats as float4)
        ((float4*)w2s)[t - 256] = ((const float4*)w2)[t - 256];
    }
    __syncthreads();

    // ---- stage 1: 8*14 = 112 outputs, depth split 4-way (16 i's each) ----
    if (t < 448) {
        const int quarter = t / 112;   // 0..3 -> i in [16q, 16q+16)
        const int r = t % 112;
        const int o = r / 14;          // 0..7  (group channel -> stage-2 'j')
        const int n = r % 14;
        const int ibase = quarter * 16;
        float acc = 0.f;
        #pragma unroll
        for (int j = 0; j < 3; ++j) {
            const int hp = m + j - 1;          // padded-H index (uniform per block)
            if (hp >= 0 && hp < 14) {
                const int row = (hp + 13) % 14;    // undo roll(+1)
                const float* xp = x + (size_t)(ibase * 8 + o) * 196 + row * 14 + n;
                const float* wp = w1s + ibase * 3 + j;
                #pragma unroll
                for (int i = 0; i < 16; ++i) {
                    acc += xp[(size_t)i * 8 * 196] * wp[i * 3];
                }
            }
        }
        t4p[quarter][r] = acc;
    }
    __syncthreads();
    if (t < 112) t4s[t] = (t4p[0][t] + t4p[1][t]) + (t4p[2][t] + t4p[3][t]);
    __syncthreads();

    // ---- stage 2: 32*14 = 448 outputs, one per thread ----
    if (t < 448) {
        const int n  = t % 14;
        const int i2 = t / 14;   // 0..31
        const float* wp = w2s + i2 * 24;
        float acc = 0.f;
        #pragma unroll
        for (int j = 0; j < 8; ++j) {
            const float* tp = t4s + j * 14;
            #pragma unroll
            for (int k = 0; k < 3; ++k) {
                const int nn = n + k - 1;
                if (nn >= 0 && nn < 14) acc += tp[nn] * wp[j * 3 + k];
            }
        }
        out[((size_t)(i2 * 16 + o2) * 14 + m) * 14 + n] = acc;
    }
}

extern "C" void kernel_launch(void* const* d_in, const int* in_sizes, int n_in,
                              void* d_out, int out_size, void* d_ws, size_t ws_size,
                              hipStream_t stream) {
    const float* x  = (const float*)d_in[0];
    const float* w1 = (const float*)d_in[1];
    const float* w2 = (const float*)d_in[2];
    float* out = (float*)d_out;
    fused_shift_conv<<<dim3(224), dim3(512), 0, stream>>>(x, w1, w2, out);
}